// Round 2
// baseline (1695.145 us; speedup 1.0000x reference)
//
#include <hip/hip_runtime.h>
#include <math.h>

#define B_ 2
#define T_ 512
#define DM_ 1024
#define DH_ 4096
#define DD_ 4
#define V_ 32000
#define M_ 4096      // B*T*DD
#define BT_ 1024     // B*T
#define NCHUNK_ 250  // V_/128

typedef __attribute__((ext_vector_type(8))) unsigned short ushort8_t;
typedef __attribute__((ext_vector_type(4))) unsigned short ushort4_t;
typedef __attribute__((ext_vector_type(8))) __bf16 bf16x8;
typedef __attribute__((ext_vector_type(4))) float f32x4;

__device__ __forceinline__ unsigned short f2bf(float x) {
  union { float f; unsigned u; } v; v.f = x;
  unsigned r = v.u + 0x7fffu + ((v.u >> 16) & 1u);
  return (unsigned short)(r >> 16);
}
__device__ __forceinline__ float bf2f(unsigned short h) {
  union { unsigned u; float f; } v; v.u = ((unsigned)h) << 16; return v.f;
}

__device__ __forceinline__ void gload16(const void* g, void* l) {
  __builtin_amdgcn_global_load_lds(
      (const __attribute__((address_space(1))) void*)g,
      (__attribute__((address_space(3))) void*)l, 16, 0, 0);
}

// Stage one 128x32 bf16 tile (row-major, leading dim ld) into linear LDS [128][32].
// Wave-uniform LDS base + lane*16 (global_load_lds contract); per-lane global src.
__device__ __forceinline__ void stage_tile(const unsigned short* src, int ld,
                                           unsigned short* lds, int wid, int lane) {
  #pragma unroll
  for (int c = 0; c < 2; ++c) {
    const int rbase = c * 64 + wid * 16;                       // wave-uniform
    const unsigned short* g = src + (size_t)(rbase + (lane >> 2)) * ld + (lane & 3) * 8;
    gload16(g, lds + rbase * 32);
  }
}

__device__ __forceinline__ float block_sum256(float v, float* sh) {
  #pragma unroll
  for (int o = 32; o >= 1; o >>= 1) v += __shfl_down(v, o);
  int lane = threadIdx.x & 63, wid = threadIdx.x >> 6;
  if (lane == 0) sh[wid] = v;
  __syncthreads();
  float t = sh[0] + sh[1] + sh[2] + sh[3];
  __syncthreads();
  return t;
}

// Transpose f32 (R,C) -> split bf16 hi/lo (C,R). lo may be null.
__global__ __launch_bounds__(256) void transpose_split_kernel(
    const float* __restrict__ in, int R, int C,
    unsigned short* __restrict__ out_hi, unsigned short* __restrict__ out_lo)
{
  __shared__ float tile[32][33];
  int c0 = blockIdx.x * 32, r0 = blockIdx.y * 32;
  int tx = threadIdx.x & 31, ty = threadIdx.x >> 5;   // 32 x 8
  #pragma unroll
  for (int i = 0; i < 4; ++i)
    tile[ty + i * 8][tx] = in[(size_t)(r0 + ty + i * 8) * C + c0 + tx];
  __syncthreads();
  #pragma unroll
  for (int i = 0; i < 4; ++i) {
    int orow = c0 + ty + i * 8;
    int ocol = r0 + tx;
    float v = tile[tx][ty + i * 8];
    unsigned short h = f2bf(v);
    out_hi[(size_t)orow * R + ocol] = h;
    if (out_lo) out_lo[(size_t)orow * R + ocol] = f2bf(v - bf2f(h));
  }
}

// Per-row embed + LayerNorm -> split bf16 X (M, DM)
__global__ __launch_bounds__(256) void embed_ln_kernel(
    const float* __restrict__ H, const int* __restrict__ ids,
    const float* __restrict__ emb, const float* __restrict__ demb,
    const float* __restrict__ g, const float* __restrict__ be,
    unsigned short* __restrict__ Xhi, unsigned short* __restrict__ Xlo)
{
  __shared__ float sh[8];
  int m = blockIdx.x, tid = threadIdx.x;
  int bt = m >> 2, d = m & 3;
  int id = ids[bt];
  float4 x  = ((const float4*)(H   + (size_t)bt * DM_))[tid];
  float4 e  = ((const float4*)(emb + (size_t)id * DM_))[tid];
  float4 de = ((const float4*)(demb + (size_t)d * DM_))[tid];
  float v0 = x.x + e.x + de.x, v1 = x.y + e.y + de.y;
  float v2 = x.z + e.z + de.z, v3 = x.w + e.w + de.w;
  float mu = block_sum256((v0 + v1) + (v2 + v3), sh) * (1.0f / DM_);
  float d0 = v0 - mu, d1v = v1 - mu, d2 = v2 - mu, d3 = v3 - mu;
  float var = block_sum256((d0 * d0 + d1v * d1v) + (d2 * d2 + d3 * d3), sh) * (1.0f / DM_);
  float rs = rsqrtf(var + 1e-5f);
  float4 gg  = ((const float4*)g)[tid];
  float4 bb4 = ((const float4*)be)[tid];
  float y0 = d0 * rs * gg.x + bb4.x;
  float y1 = d1v * rs * gg.y + bb4.y;
  float y2 = d2 * rs * gg.z + bb4.z;
  float y3 = d3 * rs * gg.w + bb4.w;
  unsigned short h0 = f2bf(y0), h1 = f2bf(y1), h2 = f2bf(y2), h3 = f2bf(y3);
  ushort4_t hv = {h0, h1, h2, h3};
  ushort4_t lv = {f2bf(y0 - bf2f(h0)), f2bf(y1 - bf2f(h1)), f2bf(y2 - bf2f(h2)), f2bf(y3 - bf2f(h3))};
  size_t base = (size_t)m * DM_ + tid * 4;
  *(ushort4_t*)&Xhi[base] = hv;
  *(ushort4_t*)&Xlo[base] = lv;
}

// w2b[j] = sum_i W2[j,i]*Wb[i]  (j<DH) ; w2b[DH] = b2.Wb + bb
__global__ __launch_bounds__(64) void w2b_kernel(
    const float* __restrict__ W2, const float* __restrict__ Wb,
    const float* __restrict__ b2, const float* __restrict__ bb,
    float* __restrict__ w2b)
{
  int j = blockIdx.x, lane = threadIdx.x;
  const float* rowp = (j < DH_) ? (W2 + (size_t)j * DM_) : b2;
  const float4* r4 = (const float4*)rowp;
  const float4* w4 = (const float4*)Wb;
  float s = 0.0f;
  for (int i = lane; i < DM_ / 4; i += 64) {
    float4 a = r4[i], w = w4[i];
    s += a.x * w.x + a.y * w.y + a.z * w.z + a.w * w.w;
  }
  #pragma unroll
  for (int o = 32; o >= 1; o >>= 1) s += __shfl_down(s, o);
  if (lane == 0) w2b[j] = (j < DH_) ? s : (s + bb[0]);
}

// C = A @ B_stored^T (+bias)(+GELU). A (M,K), B (N,K), bf16 hi/lo.
// SPLIT: 3-term hi/lo product (~f32 accuracy). m97-style: 128x128 tile, BK=32,
// global_load_lds(16) staging into linear LDS, 4 waves, 2 barriers/K-step.
// CEPART: emit per-(row, n-chunk) softmax partials (max, sumexp).
// BETAPART: emit per-(row, n-chunk) partial dot with w2bv.
// NTC: nontemporal f32 C stores (q is never bulk-re-read).
template<bool SPLIT, bool GELU, bool CEPART, bool BETAPART, bool NTC>
__global__ __launch_bounds__(256) void gemm_kernel(
    const unsigned short* __restrict__ Ahi, const unsigned short* __restrict__ Alo,
    const unsigned short* __restrict__ Bhi, const unsigned short* __restrict__ Blo,
    const float* __restrict__ bias, int Ndim, int Kdim,
    float* __restrict__ Cf, unsigned short* __restrict__ Chi, unsigned short* __restrict__ Clo,
    const int* __restrict__ rowmask,
    const float* __restrict__ w2bv, float* __restrict__ bpart,
    float* __restrict__ pmax, float* __restrict__ psum)
{
  __shared__ __align__(16) unsigned short sAhi[128 * 32];
  __shared__ __align__(16) unsigned short sBhi[128 * 32];
  __shared__ __align__(16) unsigned short sAlo[SPLIT ? 128 * 32 : 8];
  __shared__ __align__(16) unsigned short sBlo[SPLIT ? 128 * 32 : 8];
  __shared__ float red[(CEPART || BETAPART) ? 512 : 8];  // [wr][r64][wc][2] flat

  const int m0 = blockIdx.x * 128, n0 = blockIdx.y * 128;  // x = m-tile (B-tile L2 reuse)
  const int tid = threadIdx.x, lane = tid & 63, wid = tid >> 6;
  const int wr = wid >> 1, wc = wid & 1;
  const int lrow = lane & 15, koff = (lane >> 4) * 8, q4 = lane >> 4;

  const unsigned short* Ab  = Ahi + (size_t)m0 * Kdim;
  const unsigned short* Bb  = Bhi + (size_t)n0 * Kdim;
  const unsigned short* Alb = SPLIT ? (Alo + (size_t)m0 * Kdim) : nullptr;
  const unsigned short* Blb = SPLIT ? (Blo + (size_t)n0 * Kdim) : nullptr;

  f32x4 acc[4][4] = {};

  for (int k0 = 0; k0 < Kdim; k0 += 32) {
    __syncthreads();                       // previous tile fully consumed
    stage_tile(Ab + k0, Kdim, sAhi, wid, lane);
    stage_tile(Bb + k0, Kdim, sBhi, wid, lane);
    if constexpr (SPLIT) {
      stage_tile(Alb + k0, Kdim, sAlo, wid, lane);
      stage_tile(Blb + k0, Kdim, sBlo, wid, lane);
    }
    asm volatile("s_waitcnt vmcnt(0)" ::: "memory");
    __syncthreads();

    bf16x8 ah[4], bh[4], al[4], bl[4];
    #pragma unroll
    for (int i = 0; i < 4; ++i) {
      ah[i] = __builtin_bit_cast(bf16x8, *(const ushort8_t*)&sAhi[(wr * 64 + i * 16 + lrow) * 32 + koff]);
      bh[i] = __builtin_bit_cast(bf16x8, *(const ushort8_t*)&sBhi[(wc * 64 + i * 16 + lrow) * 32 + koff]);
      if constexpr (SPLIT) {
        al[i] = __builtin_bit_cast(bf16x8, *(const ushort8_t*)&sAlo[(wr * 64 + i * 16 + lrow) * 32 + koff]);
        bl[i] = __builtin_bit_cast(bf16x8, *(const ushort8_t*)&sBlo[(wc * 64 + i * 16 + lrow) * 32 + koff]);
      }
    }
    #pragma unroll
    for (int mi = 0; mi < 4; ++mi)
      #pragma unroll
      for (int ni = 0; ni < 4; ++ni) {
        acc[mi][ni] = __builtin_amdgcn_mfma_f32_16x16x32_bf16(ah[mi], bh[ni], acc[mi][ni], 0, 0, 0);
        if constexpr (SPLIT) {
          acc[mi][ni] = __builtin_amdgcn_mfma_f32_16x16x32_bf16(ah[mi], bl[ni], acc[mi][ni], 0, 0, 0);
          acc[mi][ni] = __builtin_amdgcn_mfma_f32_16x16x32_bf16(al[mi], bh[ni], acc[mi][ni], 0, 0, 0);
        }
      }
  }

  // ---- epilogue: finalize acc (bias, gelu, mask) and store ----
  #pragma unroll
  for (int mi = 0; mi < 4; ++mi)
    #pragma unroll
    for (int ni = 0; ni < 4; ++ni) {
      const int col = n0 + wc * 64 + ni * 16 + lrow;
      const float bv = bias ? bias[col] : 0.0f;
      #pragma unroll
      for (int r2 = 0; r2 < 4; ++r2) {
        const int gm = m0 + wr * 64 + mi * 16 + q4 * 4 + r2;
        float v = acc[mi][ni][r2] + bv;
        if constexpr (GELU) v = 0.5f * v * (1.0f + erff(v * 0.70710678118654752440f));
        if (rowmask) v *= (rowmask[gm >> 2] ? 1.0f : 0.0f);
        acc[mi][ni][r2] = v;
        const size_t idx = (size_t)gm * Ndim + col;
        if (Cf) {
          if constexpr (NTC) __builtin_nontemporal_store(v, &Cf[idx]);
          else Cf[idx] = v;
        }
        if (Chi) {
          unsigned short h = f2bf(v);
          Chi[idx] = h;
          if (Clo) Clo[idx] = f2bf(v - bf2f(h));
        }
      }
    }

  if constexpr (CEPART) {
    // per-row (max, sumexp) over this block's 128 columns
    #pragma unroll
    for (int mi = 0; mi < 4; ++mi)
      #pragma unroll
      for (int r2 = 0; r2 < 4; ++r2) {
        float mx = fmaxf(fmaxf(acc[mi][0][r2], acc[mi][1][r2]),
                         fmaxf(acc[mi][2][r2], acc[mi][3][r2]));
        #pragma unroll
        for (int o = 1; o < 16; o <<= 1) mx = fmaxf(mx, __shfl_xor(mx, o));
        float sm = 0.0f;
        #pragma unroll
        for (int ni = 0; ni < 4; ++ni) sm += expf(acc[mi][ni][r2] - mx);
        #pragma unroll
        for (int o = 1; o < 16; o <<= 1) sm += __shfl_xor(sm, o);
        if (lrow == 0) {
          int r64 = mi * 16 + q4 * 4 + r2;
          red[((wr * 64 + r64) * 2 + wc) * 2 + 0] = mx;
          red[((wr * 64 + r64) * 2 + wc) * 2 + 1] = sm;
        }
      }
    __syncthreads();
    if (tid < 128) {
      int wr2 = tid >> 6, r64 = tid & 63;
      float ma = red[((wr2 * 64 + r64) * 2 + 0) * 2 + 0], sa = red[((wr2 * 64 + r64) * 2 + 0) * 2 + 1];
      float mb = red[((wr2 * 64 + r64) * 2 + 1) * 2 + 0], sb = red[((wr2 * 64 + r64) * 2 + 1) * 2 + 1];
      float mg = fmaxf(ma, mb);
      float sg = sa * expf(ma - mg) + sb * expf(mb - mg);
      int grow = m0 + wr2 * 64 + r64;
      pmax[(size_t)grow * 256 + blockIdx.y] = mg;
      psum[(size_t)grow * 256 + blockIdx.y] = sg;
    }
  }

  if constexpr (BETAPART) {
    #pragma unroll
    for (int mi = 0; mi < 4; ++mi)
      #pragma unroll
      for (int r2 = 0; r2 < 4; ++r2) {
        float s = 0.0f;
        #pragma unroll
        for (int ni = 0; ni < 4; ++ni) {
          const int col = n0 + wc * 64 + ni * 16 + lrow;
          s += acc[mi][ni][r2] * w2bv[col];
        }
        #pragma unroll
        for (int o = 1; o < 16; o <<= 1) s += __shfl_xor(s, o);
        if (lrow == 0)
          red[((wr * 64 + mi * 16 + q4 * 4 + r2) * 2 + wc) * 2 + 0] = s;
      }
    __syncthreads();
    if (tid < 128) {
      int wr2 = tid >> 6, r64 = tid & 63;
      float s = red[((wr2 * 64 + r64) * 2 + 0) * 2 + 0] + red[((wr2 * 64 + r64) * 2 + 1) * 2 + 0];
      bpart[(size_t)(m0 + wr2 * 64 + r64) * 32 + blockIdx.y] = s;
    }
  }
}

// beta from 32 partial dots; k, bce, valid flags
__global__ __launch_bounds__(64) void beta_k_kernel(
    const float* __restrict__ bpart, const float* __restrict__ w2b,
    const int* __restrict__ mask,
    float* __restrict__ beta_out, float* __restrict__ k_out,
    float* __restrict__ bce, int* __restrict__ validf)
{
  int m = blockIdx.x, lane = threadIdx.x;
  float s = (lane < 32) ? bpart[(size_t)m * 32 + lane] : 0.0f;
  #pragma unroll
  for (int o = 32; o >= 1; o >>= 1) s += __shfl_down(s, o);
  if (lane == 0) {
    int bt = m >> 2, d1 = (m & 3) + 1;
    float beta = s + w2b[DH_];
    int mv = mask[bt];
    float bm = mv ? beta : 0.0f;
    int t = bt % T_;
    int valid = (t + d1 < T_) && mv && mask[bt + d1];
    beta_out[m] = bm;
    float sp = fmaxf(bm, 0.0f) + log1pf(expf(-fabsf(bm)));
    bce[m] = sp - (valid ? bm : 0.0f);
    validf[m] = valid;
    float sig = 1.0f / (1.0f + expf(-bm));
    int kk = (int)ceilf(sig * 8.0f);
    kk = kk < 1 ? 1 : (kk > 8 ? 8 : kk);
    if (!(sig >= 0.25f)) kk = 0;
    if (!mv) kk = 0;
    k_out[m] = (float)kk;
  }
}

// combine per-chunk (max, sumexp) partials -> nll per row
__global__ __launch_bounds__(64) void ce_reduce_kernel(
    const float* __restrict__ pmax, const float* __restrict__ psum,
    const float* __restrict__ q, const int* __restrict__ validf,
    const int* __restrict__ labels, float* __restrict__ nll)
{
  int m = blockIdx.x, lane = threadIdx.x;
  if (!validf[m]) { if (lane == 0) nll[m] = 0.0f; return; }
  float ml = -3.4e38f, sl = 0.0f;
  for (int j = lane; j < NCHUNK_; j += 64) {
    float mj = pmax[(size_t)m * 256 + j], sj = psum[(size_t)m * 256 + j];
    float nm = fmaxf(ml, mj);
    sl = sl * expf(ml - nm) + sj * expf(mj - nm);
    ml = nm;
  }
  #pragma unroll
  for (int o = 32; o >= 1; o >>= 1) {
    float mo = __shfl_xor(ml, o), so = __shfl_xor(sl, o);
    float nm = fmaxf(ml, mo);
    sl = sl * expf(ml - nm) + so * expf(mo - nm);
    ml = nm;
  }
  if (lane == 0) {
    int bt = m >> 2, d1 = (m & 3) + 1;
    float qt = q[(size_t)m * V_ + labels[bt + d1]];
    nll[m] = -(qt - ml - logf(sl));
  }
}

__global__ __launch_bounds__(256) void loss_kernel(
    const float* __restrict__ nll, const int* __restrict__ validf,
    const float* __restrict__ bce, float* __restrict__ loss_out)
{
  __shared__ float sh[8];
  int tid = threadIdx.x;
  float snll = 0.0f, fcnt = 0.0f, sbce = 0.0f, fnsrc = 0.0f;
  for (int m = tid; m < M_; m += 256) { snll += nll[m]; fcnt += (float)validf[m]; }
  for (int bt = tid; bt < BT_; bt += 256) {
    int base = bt * 4;
    int src = validf[base] | validf[base + 1] | validf[base + 2] | validf[base + 3];
    if (src) { sbce += bce[base] + bce[base + 1] + bce[base + 2] + bce[base + 3]; fnsrc += 1.0f; }
  }
  snll = block_sum256(snll, sh);
  fcnt = block_sum256(fcnt, sh);
  sbce = block_sum256(sbce, sh);
  fnsrc = block_sum256(fnsrc, sh);
  if (tid == 0) {
    float Lq = fcnt > 0.0f ? snll / fcnt : 0.0f;
    float Lb = sbce / fmaxf(fnsrc, 1.0f);
    loss_out[0] = Lq + Lb;
  }
}

extern "C" void kernel_launch(void* const* d_in, const int* in_sizes, int n_in,
                              void* d_out, int out_size, void* d_ws, size_t ws_size,
                              hipStream_t stream) {
  const float* H    = (const float*)d_in[0];
  const int*   ids  = (const int*)d_in[1];
  const int*   mask = (const int*)d_in[2];
  const int*   labels = (const int*)d_in[3];
  const float* emb  = (const float*)d_in[4];
  const float* demb = (const float*)d_in[5];
  const float* ln_g = (const float*)d_in[6];
  const float* ln_b = (const float*)d_in[7];
  const float* W1   = (const float*)d_in[8];
  const float* b1   = (const float*)d_in[9];
  const float* W2   = (const float*)d_in[10];
  const float* b2   = (const float*)d_in[11];
  const float* Wq   = (const float*)d_in[12];
  const float* bq   = (const float*)d_in[13];
  const float* Wb   = (const float*)d_in[14];
  const float* bb   = (const float*)d_in[15];

  char* ws = (char*)d_ws; size_t off = 0;
  auto walloc = [&](size_t bytes) -> void* {
    void* p = ws + off; off = (off + bytes + 255) & ~(size_t)255; return p;
  };
  unsigned short* W1t_hi = (unsigned short*)walloc((size_t)DH_ * DM_ * 2);
  unsigned short* W1t_lo = (unsigned short*)walloc((size_t)DH_ * DM_ * 2);
  unsigned short* W2t_hi = (unsigned short*)walloc((size_t)DM_ * DH_ * 2);
  unsigned short* W2t_lo = (unsigned short*)walloc((size_t)DM_ * DH_ * 2);
  unsigned short* Wqt_hi = (unsigned short*)walloc((size_t)V_ * DM_ * 2);
  unsigned short* Xhi    = (unsigned short*)walloc((size_t)M_ * DM_ * 2);
  unsigned short* Xlo    = (unsigned short*)walloc((size_t)M_ * DM_ * 2);
  unsigned short* S2hi   = (unsigned short*)walloc((size_t)M_ * DM_ * 2);
  float* w2b    = (float*)walloc((DH_ + 1) * 4);
  float* bpart  = (float*)walloc((size_t)M_ * 32 * 4);
  float* pmax   = (float*)walloc((size_t)M_ * 256 * 4);
  float* psum   = (float*)walloc((size_t)M_ * 256 * 4);
  float* nll    = (float*)walloc(M_ * 4);
  float* bcev   = (float*)walloc(M_ * 4);
  int*   validf = (int*)walloc(M_ * 4);

  float* q_out    = (float*)d_out;
  float* beta_out = q_out + (size_t)M_ * V_;
  float* k_out    = beta_out + M_;
  float* loss_out = k_out + M_;
  // GELU activations live in d_out's q region (overwritten later by q)
  unsigned short* act_hi = (unsigned short*)d_out;
  unsigned short* act_lo = act_hi + (size_t)M_ * DH_;

  // 1) weight transposes + splits
  transpose_split_kernel<<<dim3(DH_ / 32, DM_ / 32), 256, 0, stream>>>(W1, DM_, DH_, W1t_hi, W1t_lo);
  transpose_split_kernel<<<dim3(DM_ / 32, DH_ / 32), 256, 0, stream>>>(W2, DH_, DM_, W2t_hi, W2t_lo);
  transpose_split_kernel<<<dim3(V_ / 32, DM_ / 32), 256, 0, stream>>>(Wq, DM_, V_, Wqt_hi, nullptr);
  // 2) embed + LN
  embed_ln_kernel<<<M_, 256, 0, stream>>>(H, ids, emb, demb, ln_g, ln_b, Xhi, Xlo);
  // 3) w2b fold
  w2b_kernel<<<DH_ + 1, 64, 0, stream>>>(W2, Wb, b2, bb, w2b);
  // 4) GEMM1: act = gelu(X @ W1 + b1), split; beta partials fused
  gemm_kernel<true, true, false, true, false><<<dim3(M_ / 128, DH_ / 128), 256, 0, stream>>>(
      Xhi, Xlo, W1t_hi, W1t_lo, b1, DH_, DM_, nullptr, act_hi, act_lo, nullptr,
      w2b, bpart, nullptr, nullptr);
  // 5) beta/k/bce from partials
  beta_k_kernel<<<M_, 64, 0, stream>>>(bpart, w2b, mask, beta_out, k_out, bcev, validf);
  // 6) GEMM2: S2 = act @ W2 + b2, split, bf16-hi output
  gemm_kernel<true, false, false, false, false><<<dim3(M_ / 128, DM_ / 128), 256, 0, stream>>>(
      act_hi, act_lo, W2t_hi, W2t_lo, b2, DM_, DH_, nullptr, S2hi, nullptr, nullptr,
      nullptr, nullptr, nullptr, nullptr);
  // 7) GEMM3: q = (S2 @ Wq + bq) * mask, NT stores; CE partials fused
  gemm_kernel<false, false, true, false, true><<<dim3(M_ / 128, V_ / 128), 256, 0, stream>>>(
      S2hi, nullptr, Wqt_hi, nullptr, bq, V_, DM_, q_out, nullptr, nullptr, mask,
      nullptr, nullptr, pmax, psum);
  // 8) CE combine
  ce_reduce_kernel<<<M_, 64, 0, stream>>>(pmax, psum, q_out, validf, labels, nll);
  // 9) final loss
  loss_kernel<<<1, 256, 0, stream>>>(nll, validf, bcev, loss_out);
}

// Round 5
// 1497.452 us; speedup vs baseline: 1.1320x; 1.1320x over previous
//
#include <hip/hip_runtime.h>
#include <math.h>

#define B_ 2
#define T_ 512
#define DM_ 1024
#define DH_ 4096
#define DD_ 4
#define V_ 32000
#define M_ 4096      // B*T*DD
#define BT_ 1024     // B*T
#define NCHUNK3_ 125 // V_/256
#define PCH_ 128     // pmax/psum row stride

typedef __attribute__((ext_vector_type(8))) unsigned short ushort8_t;
typedef __attribute__((ext_vector_type(4))) unsigned short ushort4_t;
typedef __attribute__((ext_vector_type(8))) __bf16 bf16x8;
typedef __attribute__((ext_vector_type(4))) float f32x4;

__device__ __forceinline__ unsigned short f2bf(float x) {
  union { float f; unsigned u; } v; v.f = x;
  unsigned r = v.u + 0x7fffu + ((v.u >> 16) & 1u);
  return (unsigned short)(r >> 16);
}
__device__ __forceinline__ float bf2f(unsigned short h) {
  union { unsigned u; float f; } v; v.u = ((unsigned)h) << 16; return v.f;
}

__device__ __forceinline__ void gload16(const void* g, void* l) {
  __builtin_amdgcn_global_load_lds(
      (const __attribute__((address_space(1))) void*)g,
      (__attribute__((address_space(3))) void*)l, 16, 0, 0);
}

// Stage a ROWSx32 bf16 tile (row-major, leading dim ld) into LDS with
// XOR-swizzle slot' = slot ^ ((row>>1)&3).  LDS dest is linear (gload_lds
// contract: wave-uniform base + lane*16); the swizzle is applied by
// pre-swizzling the per-lane GLOBAL source column (rule 21).
// Each wave-load covers 16 rows (64 lanes x 16B = 1KB, rows are 64B).
template<int ROWS, int NWAVE>
__device__ __forceinline__ void stage_swz(const unsigned short* __restrict__ src, int ld,
                                          unsigned short* lds, int wid, int lane) {
  constexpr int NLOAD = ROWS / (16 * NWAVE);
  const int rl = lane >> 2;                       // row within 16-row chunk
  const int slot = (lane & 3) ^ ((lane >> 3) & 3);  // pre-swizzled 16B slot
  #pragma unroll
  for (int i = 0; i < NLOAD; ++i) {
    const int rbase = (i * NWAVE + wid) * 16;     // wave-uniform
    gload16(src + (size_t)(rbase + rl) * ld + slot * 8, lds + rbase * 32);
  }
}

// Read one bf16x8 fragment at (row r, 16B slot s) honoring the swizzle.
__device__ __forceinline__ bf16x8 ldfrag(const unsigned short* t, int r, int s) {
  return __builtin_bit_cast(bf16x8,
      *(const ushort8_t*)&t[r * 32 + ((s ^ ((r >> 1) & 3)) * 8)]);
}

__device__ __forceinline__ float block_sum256(float v, float* sh) {
  #pragma unroll
  for (int o = 32; o >= 1; o >>= 1) v += __shfl_down(v, o);
  int lane = threadIdx.x & 63, wid = threadIdx.x >> 6;
  if (lane == 0) sh[wid] = v;
  __syncthreads();
  float t = sh[0] + sh[1] + sh[2] + sh[3];
  __syncthreads();
  return t;
}

// Transpose f32 (R,C) -> split bf16 hi/lo (C,R). lo may be null.
__global__ __launch_bounds__(256) void transpose_split_kernel(
    const float* __restrict__ in, int R, int C,
    unsigned short* __restrict__ out_hi, unsigned short* __restrict__ out_lo)
{
  __shared__ float tile[32][33];
  int c0 = blockIdx.x * 32, r0 = blockIdx.y * 32;
  int tx = threadIdx.x & 31, ty = threadIdx.x >> 5;   // 32 x 8
  #pragma unroll
  for (int i = 0; i < 4; ++i)
    tile[ty + i * 8][tx] = in[(size_t)(r0 + ty + i * 8) * C + c0 + tx];
  __syncthreads();
  #pragma unroll
  for (int i = 0; i < 4; ++i) {
    int orow = c0 + ty + i * 8;
    int ocol = r0 + tx;
    float v = tile[tx][ty + i * 8];
    unsigned short h = f2bf(v);
    out_hi[(size_t)orow * R + ocol] = h;
    if (out_lo) out_lo[(size_t)orow * R + ocol] = f2bf(v - bf2f(h));
  }
}

// Per-row embed + LayerNorm -> split bf16 X (M, DM)
__global__ __launch_bounds__(256) void embed_ln_kernel(
    const float* __restrict__ H, const int* __restrict__ ids,
    const float* __restrict__ emb, const float* __restrict__ demb,
    const float* __restrict__ g, const float* __restrict__ be,
    unsigned short* __restrict__ Xhi, unsigned short* __restrict__ Xlo)
{
  __shared__ float sh[8];
  int m = blockIdx.x, tid = threadIdx.x;
  int bt = m >> 2, d = m & 3;
  int id = ids[bt];
  float4 x  = ((const float4*)(H   + (size_t)bt * DM_))[tid];
  float4 e  = ((const float4*)(emb + (size_t)id * DM_))[tid];
  float4 de = ((const float4*)(demb + (size_t)d * DM_))[tid];
  float v0 = x.x + e.x + de.x, v1 = x.y + e.y + de.y;
  float v2 = x.z + e.z + de.z, v3 = x.w + e.w + de.w;
  float mu = block_sum256((v0 + v1) + (v2 + v3), sh) * (1.0f / DM_);
  float d0 = v0 - mu, d1v = v1 - mu, d2 = v2 - mu, d3 = v3 - mu;
  float var = block_sum256((d0 * d0 + d1v * d1v) + (d2 * d2 + d3 * d3), sh) * (1.0f / DM_);
  float rs = rsqrtf(var + 1e-5f);
  float4 gg  = ((const float4*)g)[tid];
  float4 bb4 = ((const float4*)be)[tid];
  float y0 = d0 * rs * gg.x + bb4.x;
  float y1 = d1v * rs * gg.y + bb4.y;
  float y2 = d2 * rs * gg.z + bb4.z;
  float y3 = d3 * rs * gg.w + bb4.w;
  unsigned short h0 = f2bf(y0), h1 = f2bf(y1), h2 = f2bf(y2), h3 = f2bf(y3);
  ushort4_t hv = {h0, h1, h2, h3};
  ushort4_t lv = {f2bf(y0 - bf2f(h0)), f2bf(y1 - bf2f(h1)), f2bf(y2 - bf2f(h2)), f2bf(y3 - bf2f(h3))};
  size_t base = (size_t)m * DM_ + tid * 4;
  *(ushort4_t*)&Xhi[base] = hv;
  *(ushort4_t*)&Xlo[base] = lv;
}

// w2b[j] = sum_i W2[j,i]*Wb[i]  (j<DH) ; w2b[DH] = b2.Wb + bb
__global__ __launch_bounds__(64) void w2b_kernel(
    const float* __restrict__ W2, const float* __restrict__ Wb,
    const float* __restrict__ b2, const float* __restrict__ bb,
    float* __restrict__ w2b)
{
  int j = blockIdx.x, lane = threadIdx.x;
  const float* rowp = (j < DH_) ? (W2 + (size_t)j * DM_) : b2;
  const float4* r4 = (const float4*)rowp;
  const float4* w4 = (const float4*)Wb;
  float s = 0.0f;
  for (int i = lane; i < DM_ / 4; i += 64) {
    float4 a = r4[i], w = w4[i];
    s += a.x * w.x + a.y * w.y + a.z * w.z + a.w * w.w;
  }
  #pragma unroll
  for (int o = 32; o >= 1; o >>= 1) s += __shfl_down(s, o);
  if (lane == 0) w2b[j] = (j < DH_) ? s : (s + bb[0]);
}

// 2-phase double-buffered MFMA GEMM:  C = A @ B_stored^T (+bias)(+GELU)
// A (M,K) bf16 [hi/lo], B (N,K) bf16 [hi/lo], BK=32, swizzled LDS,
// global_load_lds staging issued for tile k+1 BEFORE computing tile k
// (T3-minimum recipe: one vmcnt(0)+barrier per K-tile, loads hidden
// under current-tile MFMA).
template<int BM, int BN, int NWAVE, int WN,
         bool SPLIT, bool GELU, bool CEPART, bool BETAPART, bool NTC>
__global__ __launch_bounds__(NWAVE * 64, 2) void gemm2p_kernel(
    const unsigned short* __restrict__ Ahi, const unsigned short* __restrict__ Alo,
    const unsigned short* __restrict__ Bhi, const unsigned short* __restrict__ Blo,
    const float* __restrict__ bias, int Ndim, int Kdim,
    float* __restrict__ Cf, unsigned short* __restrict__ Chi, unsigned short* __restrict__ Clo,
    const int* __restrict__ rowmask,
    const float* __restrict__ w2bv, float* __restrict__ bpart,
    float* __restrict__ pmax, float* __restrict__ psum)
{
  constexpr int WM = NWAVE / WN;
  constexpr int MI = (BM / WM) / 16;
  constexpr int NI = (BN / WN) / 16;
  constexpr int AW = BM * 32;   // ushorts per A tile (BK=32)
  constexpr int BW = BN * 32;
  constexpr int BUFW = (SPLIT ? 2 : 1) * (AW + BW);
  __shared__ __align__(16) unsigned short smem[2 * BUFW];

  const int m0 = blockIdx.x * BM, n0 = blockIdx.y * BN;
  const int tid = threadIdx.x, lane = tid & 63, wid = tid >> 6;
  const int wr = wid / WN, wc = wid % WN;
  const int lrow = lane & 15, q4 = lane >> 4;
  const int wrb = wr * (BM / WM), wcb = wc * (BN / WN);

  const unsigned short* Ab  = Ahi + (size_t)m0 * Kdim;
  const unsigned short* Bb  = Bhi + (size_t)n0 * Kdim;
  const unsigned short* Alb = SPLIT ? (Alo + (size_t)m0 * Kdim) : nullptr;
  const unsigned short* Blb = SPLIT ? (Blo + (size_t)n0 * Kdim) : nullptr;

  f32x4 acc[MI][NI] = {};
  const int NT = Kdim / 32;

  auto stageAll = [&](int buf, int kt) {
    unsigned short* base = smem + buf * BUFW;
    const int ko = kt * 32;
    stage_swz<BM, NWAVE>(Ab + ko, Kdim, base, wid, lane);
    stage_swz<BN, NWAVE>(Bb + ko, Kdim, base + AW, wid, lane);
    if constexpr (SPLIT) {
      stage_swz<BM, NWAVE>(Alb + ko, Kdim, base + AW + BW, wid, lane);
      stage_swz<BN, NWAVE>(Blb + ko, Kdim, base + 2 * AW + BW, wid, lane);
    }
  };

  stageAll(0, 0);
  asm volatile("s_waitcnt vmcnt(0)" ::: "memory");
  __syncthreads();           // buf0 ready

  int cur = 0;
  for (int kt = 0; kt < NT; ++kt) {
    if (kt + 1 < NT) stageAll(cur ^ 1, kt + 1);
    __builtin_amdgcn_sched_barrier(0);   // keep stage issue above compute
    const unsigned short* sA = smem + cur * BUFW;
    const unsigned short* sB = sA + AW;
    bf16x8 bh[NI], bl[NI];
    #pragma unroll
    for (int ni = 0; ni < NI; ++ni) {
      bh[ni] = ldfrag(sB, wcb + ni * 16 + lrow, q4);
      if constexpr (SPLIT) bl[ni] = ldfrag(sB + AW + BW, wcb + ni * 16 + lrow, q4);
    }
    #pragma unroll
    for (int mi = 0; mi < MI; ++mi) {
      const int r = wrb + mi * 16 + lrow;
      bf16x8 ah = ldfrag(sA, r, q4);
      bf16x8 al;
      if constexpr (SPLIT) al = ldfrag(sA + AW + BW, r, q4);
      #pragma unroll
      for (int ni = 0; ni < NI; ++ni) {
        acc[mi][ni] = __builtin_amdgcn_mfma_f32_16x16x32_bf16(ah, bh[ni], acc[mi][ni], 0, 0, 0);
        if constexpr (SPLIT) {
          acc[mi][ni] = __builtin_amdgcn_mfma_f32_16x16x32_bf16(ah, bl[ni], acc[mi][ni], 0, 0, 0);
          acc[mi][ni] = __builtin_amdgcn_mfma_f32_16x16x32_bf16(al, bh[ni], acc[mi][ni], 0, 0, 0);
        }
      }
    }
    asm volatile("s_waitcnt vmcnt(0)" ::: "memory");  // prefetch landed
    __syncthreads();          // all waves past reads of cur; next buf ready
    cur ^= 1;
  }

  // ---- epilogue: finalize acc (bias, gelu, mask) and store ----
  #pragma unroll
  for (int mi = 0; mi < MI; ++mi)
    #pragma unroll
    for (int ni = 0; ni < NI; ++ni) {
      const int col = n0 + wcb + ni * 16 + lrow;
      const float bv = bias ? bias[col] : 0.0f;
      #pragma unroll
      for (int r2 = 0; r2 < 4; ++r2) {
        const int gm = m0 + wrb + mi * 16 + q4 * 4 + r2;
        float v = acc[mi][ni][r2] + bv;
        if constexpr (GELU) v = 0.5f * v * (1.0f + erff(v * 0.70710678118654752440f));
        if (rowmask) v *= (rowmask[gm >> 2] ? 1.0f : 0.0f);
        acc[mi][ni][r2] = v;
        const size_t idx = (size_t)gm * Ndim + col;
        if (Cf) {
          if constexpr (NTC) __builtin_nontemporal_store(v, &Cf[idx]);
          else Cf[idx] = v;
        }
        if (Chi) {
          unsigned short h = f2bf(v);
          Chi[idx] = h;
          if (Clo) Clo[idx] = f2bf(v - bf2f(h));
        }
      }
    }

  float* red = (float*)smem;   // staging LDS reused after final barrier

  if constexpr (CEPART) {
    #pragma unroll
    for (int mi = 0; mi < MI; ++mi)
      #pragma unroll
      for (int r2 = 0; r2 < 4; ++r2) {
        float mx = -3.4e38f;
        #pragma unroll
        for (int ni = 0; ni < NI; ++ni) mx = fmaxf(mx, acc[mi][ni][r2]);
        #pragma unroll
        for (int o = 1; o < 16; o <<= 1) mx = fmaxf(mx, __shfl_xor(mx, o));
        float sm = 0.0f;
        #pragma unroll
        for (int ni = 0; ni < NI; ++ni) sm += expf(acc[mi][ni][r2] - mx);
        #pragma unroll
        for (int o = 1; o < 16; o <<= 1) sm += __shfl_xor(sm, o);
        if (lrow == 0) {
          const int rowL = wrb + mi * 16 + q4 * 4 + r2;
          red[(rowL * WN + wc) * 2 + 0] = mx;
          red[(rowL * WN + wc) * 2 + 1] = sm;
        }
      }
    __syncthreads();
    for (int r = tid; r < BM; r += NWAVE * 64) {
      float mg = -3.4e38f, sg = 0.0f;
      #pragma unroll
      for (int w = 0; w < WN; ++w) {
        float mw = red[(r * WN + w) * 2 + 0], sw = red[(r * WN + w) * 2 + 1];
        float nm = fmaxf(mg, mw);
        sg = sg * expf(mg - nm) + sw * expf(mw - nm);
        mg = nm;
      }
      pmax[(size_t)(m0 + r) * PCH_ + blockIdx.y] = mg;
      psum[(size_t)(m0 + r) * PCH_ + blockIdx.y] = sg;
    }
  }

  if constexpr (BETAPART) {
    #pragma unroll
    for (int mi = 0; mi < MI; ++mi)
      #pragma unroll
      for (int r2 = 0; r2 < 4; ++r2) {
        float s = 0.0f;
        #pragma unroll
        for (int ni = 0; ni < NI; ++ni)
          s += acc[mi][ni][r2] * w2bv[n0 + wcb + ni * 16 + lrow];
        #pragma unroll
        for (int o = 1; o < 16; o <<= 1) s += __shfl_xor(s, o);
        if (lrow == 0)
          red[(wrb + mi * 16 + q4 * 4 + r2) * WN + wc] = s;
      }
    __syncthreads();
    for (int r = tid; r < BM; r += NWAVE * 64) {
      float s = 0.0f;
      #pragma unroll
      for (int w = 0; w < WN; ++w) s += red[r * WN + w];
      bpart[(size_t)(m0 + r) * 32 + blockIdx.y] = s;
    }
  }
}

// beta from 32 partial dots; k, bce, valid flags
__global__ __launch_bounds__(64) void beta_k_kernel(
    const float* __restrict__ bpart, const float* __restrict__ w2b,
    const int* __restrict__ mask,
    float* __restrict__ beta_out, float* __restrict__ k_out,
    float* __restrict__ bce, int* __restrict__ validf)
{
  int m = blockIdx.x, lane = threadIdx.x;
  float s = (lane < 32) ? bpart[(size_t)m * 32 + lane] : 0.0f;
  #pragma unroll
  for (int o = 32; o >= 1; o >>= 1) s += __shfl_down(s, o);
  if (lane == 0) {
    int bt = m >> 2, d1 = (m & 3) + 1;
    float beta = s + w2b[DH_];
    int mv = mask[bt];
    float bm = mv ? beta : 0.0f;
    int t = bt % T_;
    int valid = (t + d1 < T_) && mv && mask[bt + d1];
    beta_out[m] = bm;
    float sp = fmaxf(bm, 0.0f) + log1pf(expf(-fabsf(bm)));
    bce[m] = sp - (valid ? bm : 0.0f);
    validf[m] = valid;
    float sig = 1.0f / (1.0f + expf(-bm));
    int kk = (int)ceilf(sig * 8.0f);
    kk = kk < 1 ? 1 : (kk > 8 ? 8 : kk);
    if (!(sig >= 0.25f)) kk = 0;
    if (!mv) kk = 0;
    k_out[m] = (float)kk;
  }
}

// combine per-chunk (max, sumexp) partials -> nll per row
__global__ __launch_bounds__(64) void ce_reduce_kernel(
    const float* __restrict__ pmax, const float* __restrict__ psum,
    const float* __restrict__ q, const int* __restrict__ validf,
    const int* __restrict__ labels, float* __restrict__ nll)
{
  int m = blockIdx.x, lane = threadIdx.x;
  if (!validf[m]) { if (lane == 0) nll[m] = 0.0f; return; }
  float ml = -3.4e38f, sl = 0.0f;
  for (int j = lane; j < NCHUNK3_; j += 64) {
    float mj = pmax[(size_t)m * PCH_ + j], sj = psum[(size_t)m * PCH_ + j];
    float nm = fmaxf(ml, mj);
    sl = sl * expf(ml - nm) + sj * expf(mj - nm);
    ml = nm;
  }
  #pragma unroll
  for (int o = 32; o >= 1; o >>= 1) {
    float mo = __shfl_xor(ml, o), so = __shfl_xor(sl, o);
    float nm = fmaxf(ml, mo);
    sl = sl * expf(ml - nm) + so * expf(mo - nm);
    ml = nm;
  }
  if (lane == 0) {
    int bt = m >> 2, d1 = (m & 3) + 1;
    float qt = q[(size_t)m * V_ + labels[bt + d1]];
    nll[m] = -(qt - ml - logf(sl));
  }
}

__global__ __launch_bounds__(256) void loss_kernel(
    const float* __restrict__ nll, const int* __restrict__ validf,
    const float* __restrict__ bce, float* __restrict__ loss_out)
{
  __shared__ float sh[8];
  int tid = threadIdx.x;
  float snll = 0.0f, fcnt = 0.0f, sbce = 0.0f, fnsrc = 0.0f;
  for (int m = tid; m < M_; m += 256) { snll += nll[m]; fcnt += (float)validf[m]; }
  for (int bt = tid; bt < BT_; bt += 256) {
    int base = bt * 4;
    int src = validf[base] | validf[base + 1] | validf[base + 2] | validf[base + 3];
    if (src) { sbce += bce[base] + bce[base + 1] + bce[base + 2] + bce[base + 3]; fnsrc += 1.0f; }
  }
  snll = block_sum256(snll, sh);
  fcnt = block_sum256(fcnt, sh);
  sbce = block_sum256(sbce, sh);
  fnsrc = block_sum256(fnsrc, sh);
  if (tid == 0) {
    float Lq = fcnt > 0.0f ? snll / fcnt : 0.0f;
    float Lb = sbce / fmaxf(fnsrc, 1.0f);
    loss_out[0] = Lq + Lb;
  }
}

extern "C" void kernel_launch(void* const* d_in, const int* in_sizes, int n_in,
                              void* d_out, int out_size, void* d_ws, size_t ws_size,
                              hipStream_t stream) {
  const float* H    = (const float*)d_in[0];
  const int*   ids  = (const int*)d_in[1];
  const int*   mask = (const int*)d_in[2];
  const int*   labels = (const int*)d_in[3];
  const float* emb  = (const float*)d_in[4];
  const float* demb = (const float*)d_in[5];
  const float* ln_g = (const float*)d_in[6];
  const float* ln_b = (const float*)d_in[7];
  const float* W1   = (const float*)d_in[8];
  const float* b1   = (const float*)d_in[9];
  const float* W2   = (const float*)d_in[10];
  const float* b2   = (const float*)d_in[11];
  const float* Wq   = (const float*)d_in[12];
  const float* bq   = (const float*)d_in[13];
  const float* Wb   = (const float*)d_in[14];
  const float* bb   = (const float*)d_in[15];

  char* ws = (char*)d_ws; size_t off = 0;
  auto walloc = [&](size_t bytes) -> void* {
    void* p = ws + off; off = (off + bytes + 255) & ~(size_t)255; return p;
  };
  unsigned short* W1t_hi = (unsigned short*)walloc((size_t)DH_ * DM_ * 2);
  unsigned short* W1t_lo = (unsigned short*)walloc((size_t)DH_ * DM_ * 2);
  unsigned short* W2t_hi = (unsigned short*)walloc((size_t)DM_ * DH_ * 2);
  unsigned short* Wqt_hi = (unsigned short*)walloc((size_t)V_ * DM_ * 2);
  unsigned short* Xhi    = (unsigned short*)walloc((size_t)M_ * DM_ * 2);
  unsigned short* Xlo    = (unsigned short*)walloc((size_t)M_ * DM_ * 2);
  unsigned short* S2hi   = (unsigned short*)walloc((size_t)M_ * DM_ * 2);
  float* w2b    = (float*)walloc((DH_ + 1) * 4);
  float* bpart  = (float*)walloc((size_t)M_ * 32 * 4);
  float* pmax   = (float*)walloc((size_t)M_ * PCH_ * 4);
  float* psum   = (float*)walloc((size_t)M_ * PCH_ * 4);
  float* nll    = (float*)walloc(M_ * 4);
  float* bcev   = (float*)walloc(M_ * 4);
  int*   validf = (int*)walloc(M_ * 4);

  float* q_out    = (float*)d_out;
  float* beta_out = q_out + (size_t)M_ * V_;
  float* k_out    = beta_out + M_;
  float* loss_out = k_out + M_;
  // GELU activations live in d_out's q region (overwritten later by q)
  unsigned short* act_hi = (unsigned short*)d_out;
  unsigned short* act_lo = act_hi + (size_t)M_ * DH_;

  // 1) weight transposes + splits
  transpose_split_kernel<<<dim3(DH_ / 32, DM_ / 32), 256, 0, stream>>>(W1, DM_, DH_, W1t_hi, W1t_lo);
  transpose_split_kernel<<<dim3(DM_ / 32, DH_ / 32), 256, 0, stream>>>(W2, DH_, DM_, W2t_hi, nullptr);
  transpose_split_kernel<<<dim3(V_ / 32, DM_ / 32), 256, 0, stream>>>(Wq, DM_, V_, Wqt_hi, nullptr);
  // 2) embed + LN
  embed_ln_kernel<<<M_, 256, 0, stream>>>(H, ids, emb, demb, ln_g, ln_b, Xhi, Xlo);
  // 3) w2b fold
  w2b_kernel<<<DH_ + 1, 64, 0, stream>>>(W2, Wb, b2, bb, w2b);
  // 4) GEMM1: act = gelu(X @ W1 + b1), split 3-term; beta partials fused
  //    128x128 tile, 8 waves (2x4)
  gemm2p_kernel<128, 128, 8, 4, true, true, false, true, false>
      <<<dim3(M_ / 128, DH_ / 128), 512, 0, stream>>>(
      Xhi, Xlo, W1t_hi, W1t_lo, b1, DH_, DM_, nullptr, act_hi, act_lo, nullptr,
      w2b, bpart, nullptr, nullptr);
  // 5) beta/k/bce from partials
  beta_k_kernel<<<M_, 64, 0, stream>>>(bpart, w2b, mask, beta_out, k_out, bcev, validf);
  // 6) GEMM2: S2 = act @ W2 + b2, plain bf16; 128x128, 4 waves (2x2)
  gemm2p_kernel<128, 128, 4, 2, false, false, false, false, false>
      <<<dim3(M_ / 128, DM_ / 128), 256, 0, stream>>>(
      act_hi, nullptr, W2t_hi, nullptr, b2, DM_, DH_, nullptr, S2hi, nullptr, nullptr,
      nullptr, nullptr, nullptr, nullptr);
  // 7) GEMM3: q = (S2 @ Wq + bq) * mask, NT stores; CE partials fused
  //    256x256 tile, 8 waves (2x4)
  gemm2p_kernel<256, 256, 8, 4, false, false, true, false, true>
      <<<dim3(M_ / 256, V_ / 256), 512, 0, stream>>>(
      S2hi, nullptr, Wqt_hi, nullptr, bq, V_, DM_, q_out, nullptr, nullptr, mask,
      nullptr, nullptr, pmax, psum);
  // 8) CE combine
  ce_reduce_kernel<<<M_, 64, 0, stream>>>(pmax, psum, q_out, validf, labels, nll);
  // 9) final loss
  loss_kernel<<<1, 256, 0, stream>>>(nll, validf, bcev, loss_out);
}

// Round 6
// 1391.754 us; speedup vs baseline: 1.2180x; 1.0759x over previous
//
#include <hip/hip_runtime.h>
#include <math.h>

#define B_ 2
#define T_ 512
#define DM_ 1024
#define DH_ 4096
#define DD_ 4
#define V_ 32000
#define M_ 4096      // B*T*DD
#define BT_ 1024     // B*T
#define NCHUNK3_ 125 // V_/256
#define PCH_ 128     // pmax/psum row stride

typedef __attribute__((ext_vector_type(8))) unsigned short ushort8_t;
typedef __attribute__((ext_vector_type(4))) unsigned short ushort4_t;
typedef __attribute__((ext_vector_type(8))) __bf16 bf16x8;
typedef __attribute__((ext_vector_type(4))) float f32x4;

__device__ __forceinline__ unsigned short f2bf(float x) {
  union { float f; unsigned u; } v; v.f = x;
  unsigned r = v.u + 0x7fffu + ((v.u >> 16) & 1u);
  return (unsigned short)(r >> 16);
}
__device__ __forceinline__ float bf2f(unsigned short h) {
  union { unsigned u; float f; } v; v.u = ((unsigned)h) << 16; return v.f;
}

__device__ __forceinline__ void gload16(const void* g, void* l) {
  __builtin_amdgcn_global_load_lds(
      (const __attribute__((address_space(1))) void*)g,
      (__attribute__((address_space(3))) void*)l, 16, 0, 0);
}

// Stage a ROWSx32 bf16 tile (row-major, leading dim ld) into LDS with
// XOR-swizzle slot' = slot ^ ((row>>1)&3).  LDS dest is linear (gload_lds
// contract: wave-uniform base + lane*16); the swizzle is applied by
// pre-swizzling the per-lane GLOBAL source column (rule 21).
template<int ROWS, int NWAVE>
__device__ __forceinline__ void stage_swz(const unsigned short* __restrict__ src, int ld,
                                          unsigned short* lds, int wid, int lane) {
  constexpr int NLOAD = ROWS / (16 * NWAVE);
  const int rl = lane >> 2;                         // row within 16-row chunk
  const int slot = (lane & 3) ^ ((lane >> 3) & 3);  // pre-swizzled 16B slot
  #pragma unroll
  for (int i = 0; i < NLOAD; ++i) {
    const int rbase = (i * NWAVE + wid) * 16;       // wave-uniform
    gload16(src + (size_t)(rbase + rl) * ld + slot * 8, lds + rbase * 32);
  }
}

// Read one bf16x8 fragment at (row r, 16B slot s) honoring the swizzle.
__device__ __forceinline__ bf16x8 ldfrag(const unsigned short* t, int r, int s) {
  return __builtin_bit_cast(bf16x8,
      *(const ushort8_t*)&t[r * 32 + ((s ^ ((r >> 1) & 3)) * 8)]);
}

__device__ __forceinline__ float block_sum256(float v, float* sh) {
  #pragma unroll
  for (int o = 32; o >= 1; o >>= 1) v += __shfl_down(v, o);
  int lane = threadIdx.x & 63, wid = threadIdx.x >> 6;
  if (lane == 0) sh[wid] = v;
  __syncthreads();
  float t = sh[0] + sh[1] + sh[2] + sh[3];
  __syncthreads();
  return t;
}

// Transpose f32 (R,C) -> split bf16 hi/lo (C,R). lo may be null.
__global__ __launch_bounds__(256) void transpose_split_kernel(
    const float* __restrict__ in, int R, int C,
    unsigned short* __restrict__ out_hi, unsigned short* __restrict__ out_lo)
{
  __shared__ float tile[32][33];
  int c0 = blockIdx.x * 32, r0 = blockIdx.y * 32;
  int tx = threadIdx.x & 31, ty = threadIdx.x >> 5;   // 32 x 8
  #pragma unroll
  for (int i = 0; i < 4; ++i)
    tile[ty + i * 8][tx] = in[(size_t)(r0 + ty + i * 8) * C + c0 + tx];
  __syncthreads();
  #pragma unroll
  for (int i = 0; i < 4; ++i) {
    int orow = c0 + ty + i * 8;
    int ocol = r0 + tx;
    float v = tile[tx][ty + i * 8];
    unsigned short h = f2bf(v);
    out_hi[(size_t)orow * R + ocol] = h;
    if (out_lo) out_lo[(size_t)orow * R + ocol] = f2bf(v - bf2f(h));
  }
}

// Per-row embed + LayerNorm -> split bf16 X (M, DM)
__global__ __launch_bounds__(256) void embed_ln_kernel(
    const float* __restrict__ H, const int* __restrict__ ids,
    const float* __restrict__ emb, const float* __restrict__ demb,
    const float* __restrict__ g, const float* __restrict__ be,
    unsigned short* __restrict__ Xhi, unsigned short* __restrict__ Xlo)
{
  __shared__ float sh[8];
  int m = blockIdx.x, tid = threadIdx.x;
  int bt = m >> 2, d = m & 3;
  int id = ids[bt];
  float4 x  = ((const float4*)(H   + (size_t)bt * DM_))[tid];
  float4 e  = ((const float4*)(emb + (size_t)id * DM_))[tid];
  float4 de = ((const float4*)(demb + (size_t)d * DM_))[tid];
  float v0 = x.x + e.x + de.x, v1 = x.y + e.y + de.y;
  float v2 = x.z + e.z + de.z, v3 = x.w + e.w + de.w;
  float mu = block_sum256((v0 + v1) + (v2 + v3), sh) * (1.0f / DM_);
  float d0 = v0 - mu, d1v = v1 - mu, d2 = v2 - mu, d3 = v3 - mu;
  float var = block_sum256((d0 * d0 + d1v * d1v) + (d2 * d2 + d3 * d3), sh) * (1.0f / DM_);
  float rs = rsqrtf(var + 1e-5f);
  float4 gg  = ((const float4*)g)[tid];
  float4 bb4 = ((const float4*)be)[tid];
  float y0 = d0 * rs * gg.x + bb4.x;
  float y1 = d1v * rs * gg.y + bb4.y;
  float y2 = d2 * rs * gg.z + bb4.z;
  float y3 = d3 * rs * gg.w + bb4.w;
  unsigned short h0 = f2bf(y0), h1 = f2bf(y1), h2 = f2bf(y2), h3 = f2bf(y3);
  ushort4_t hv = {h0, h1, h2, h3};
  ushort4_t lv = {f2bf(y0 - bf2f(h0)), f2bf(y1 - bf2f(h1)), f2bf(y2 - bf2f(h2)), f2bf(y3 - bf2f(h3))};
  size_t base = (size_t)m * DM_ + tid * 4;
  *(ushort4_t*)&Xhi[base] = hv;
  *(ushort4_t*)&Xlo[base] = lv;
}

// w2b[j] = sum_i W2[j,i]*Wb[i]  (j<DH) ; w2b[DH] = b2.Wb + bb
__global__ __launch_bounds__(64) void w2b_kernel(
    const float* __restrict__ W2, const float* __restrict__ Wb,
    const float* __restrict__ b2, const float* __restrict__ bb,
    float* __restrict__ w2b)
{
  int j = blockIdx.x, lane = threadIdx.x;
  const float* rowp = (j < DH_) ? (W2 + (size_t)j * DM_) : b2;
  const float4* r4 = (const float4*)rowp;
  const float4* w4 = (const float4*)Wb;
  float s = 0.0f;
  for (int i = lane; i < DM_ / 4; i += 64) {
    float4 a = r4[i], w = w4[i];
    s += a.x * w.x + a.y * w.y + a.z * w.z + a.w * w.w;
  }
  #pragma unroll
  for (int o = 32; o >= 1; o >>= 1) s += __shfl_down(s, o);
  if (lane == 0) w2b[j] = (j < DH_) ? s : (s + bb[0]);
}

// 3-deep counted-vmcnt pipelined MFMA GEMM:  C = A @ B_stored^T (+bias)(+GELU)
// A (M,K) bf16 [hi/lo], B (N,K) bf16 [hi/lo], BK=32, swizzled LDS.
// Steady state per K-step: vmcnt(4) [stage k landed, k+1 in flight] ->
// raw s_barrier (NO full drain) -> issue stage k+2 -> ds_read+MFMA on buf k.
// Never drains vmcnt to 0 in the loop (T4); prefetch distance = 2 compute phases.
template<int BM, int BN, int NWAVE, int WN,
         bool SPLIT, bool GELU, bool CEPART, bool BETAPART, bool NTC>
__global__ __launch_bounds__(NWAVE * 64, 2) void gemm3p_kernel(
    const unsigned short* __restrict__ Ahi, const unsigned short* __restrict__ Alo,
    const unsigned short* __restrict__ Bhi, const unsigned short* __restrict__ Blo,
    const float* __restrict__ bias, int Ndim, int Kdim,
    float* __restrict__ Cf, unsigned short* __restrict__ Chi, unsigned short* __restrict__ Clo,
    const int* __restrict__ rowmask,
    const float* __restrict__ w2bv, float* __restrict__ bpart,
    float* __restrict__ pmax, float* __restrict__ psum)
{
  constexpr int WM = NWAVE / WN;
  constexpr int MI = (BM / WM) / 16;
  constexpr int NI = (BN / WN) / 16;
  constexpr int AW = BM * 32;   // ushorts per A tile (BK=32)
  constexpr int BW = BN * 32;
  constexpr int BUFW = (SPLIT ? 2 : 1) * (AW + BW);
  constexpr int LPS = (SPLIT ? 2 : 1) * (BM / (16 * NWAVE) + BN / (16 * NWAVE));
  static_assert(LPS == 4, "vmcnt(4) assumes exactly 4 loads per wave per stage");
  __shared__ __align__(16) unsigned short smem[3 * BUFW];

  const int m0 = blockIdx.x * BM, n0 = blockIdx.y * BN;  // x = m-tile (B-tile L2 reuse)
  const int tid = threadIdx.x, lane = tid & 63, wid = tid >> 6;
  const int wr = wid / WN, wc = wid % WN;
  const int lrow = lane & 15, q4 = lane >> 4;
  const int wrb = wr * (BM / WM), wcb = wc * (BN / WN);

  const unsigned short* Ab  = Ahi + (size_t)m0 * Kdim;
  const unsigned short* Bb  = Bhi + (size_t)n0 * Kdim;
  const unsigned short* Alb = SPLIT ? (Alo + (size_t)m0 * Kdim) : nullptr;
  const unsigned short* Blb = SPLIT ? (Blo + (size_t)n0 * Kdim) : nullptr;

  f32x4 acc[MI][NI] = {};
  const int NT = Kdim / 32;

  auto stageAll = [&](unsigned short* base, int kt) {
    const int ko = kt * 32;
    stage_swz<BM, NWAVE>(Ab + ko, Kdim, base, wid, lane);
    stage_swz<BN, NWAVE>(Bb + ko, Kdim, base + AW, wid, lane);
    if constexpr (SPLIT) {
      stage_swz<BM, NWAVE>(Alb + ko, Kdim, base + AW + BW, wid, lane);
      stage_swz<BN, NWAVE>(Blb + ko, Kdim, base + 2 * AW + BW, wid, lane);
    }
  };

  unsigned short* p0 = smem;               // current compute buffer
  unsigned short* p1 = smem + BUFW;        // next (in flight)
  unsigned short* p2 = smem + 2 * BUFW;    // next-next (to be issued)

  stageAll(p0, 0);                         // 4 loads
  stageAll(p1, 1);                         // +4 loads (NT >= 32 always here)

  for (int kt = 0; kt < NT; ++kt) {
    // Wait for stage kt only; keep stage kt+1 in flight.
    if (kt + 1 < NT) asm volatile("s_waitcnt vmcnt(4)" ::: "memory");
    else             asm volatile("s_waitcnt vmcnt(0)" ::: "memory");
    __builtin_amdgcn_s_barrier();          // raw: no compiler-forced vmcnt(0)
    __builtin_amdgcn_sched_barrier(0);
    // Issue stage kt+2 into p2 (overwrites buffer read at iter kt-1; safe:
    // those reads were lgkmcnt-consumed before each wave reached the barrier).
    if (kt + 2 < NT) stageAll(p2, kt + 2);
    __builtin_amdgcn_sched_barrier(0);

    const unsigned short* sA = p0;
    const unsigned short* sB = p0 + AW;
    bf16x8 bh[NI], bl[NI];
    #pragma unroll
    for (int ni = 0; ni < NI; ++ni) {
      bh[ni] = ldfrag(sB, wcb + ni * 16 + lrow, q4);
      if constexpr (SPLIT) bl[ni] = ldfrag(sB + AW + BW, wcb + ni * 16 + lrow, q4);
    }
    #pragma unroll
    for (int mi = 0; mi < MI; ++mi) {
      const int r = wrb + mi * 16 + lrow;
      bf16x8 ah = ldfrag(sA, r, q4);
      bf16x8 al;
      if constexpr (SPLIT) al = ldfrag(sA + AW + BW, r, q4);
      #pragma unroll
      for (int ni = 0; ni < NI; ++ni) {
        acc[mi][ni] = __builtin_amdgcn_mfma_f32_16x16x32_bf16(ah, bh[ni], acc[mi][ni], 0, 0, 0);
        if constexpr (SPLIT) {
          acc[mi][ni] = __builtin_amdgcn_mfma_f32_16x16x32_bf16(ah, bl[ni], acc[mi][ni], 0, 0, 0);
          acc[mi][ni] = __builtin_amdgcn_mfma_f32_16x16x32_bf16(al, bh[ni], acc[mi][ni], 0, 0, 0);
        }
      }
    }
    unsigned short* t = p0; p0 = p1; p1 = p2; p2 = t;   // rotate buffers
  }
  __syncthreads();   // all waves done with LDS tiles (protects 'red' reuse)

  // ---- epilogue: finalize acc (bias, gelu, mask) and store ----
  #pragma unroll
  for (int mi = 0; mi < MI; ++mi)
    #pragma unroll
    for (int ni = 0; ni < NI; ++ni) {
      const int col = n0 + wcb + ni * 16 + lrow;
      const float bv = bias ? bias[col] : 0.0f;
      #pragma unroll
      for (int r2 = 0; r2 < 4; ++r2) {
        const int gm = m0 + wrb + mi * 16 + q4 * 4 + r2;
        float v = acc[mi][ni][r2] + bv;
        if constexpr (GELU) v = 0.5f * v * (1.0f + erff(v * 0.70710678118654752440f));
        if (rowmask) v *= (rowmask[gm >> 2] ? 1.0f : 0.0f);
        acc[mi][ni][r2] = v;
        const size_t idx = (size_t)gm * Ndim + col;
        if (Cf) {
          if constexpr (NTC) __builtin_nontemporal_store(v, &Cf[idx]);
          else Cf[idx] = v;
        }
        if (Chi) {
          unsigned short h = f2bf(v);
          Chi[idx] = h;
          if (Clo) Clo[idx] = f2bf(v - bf2f(h));
        }
      }
    }

  float* red = (float*)smem;   // staging LDS reused after final barrier

  if constexpr (CEPART) {
    #pragma unroll
    for (int mi = 0; mi < MI; ++mi)
      #pragma unroll
      for (int r2 = 0; r2 < 4; ++r2) {
        float mx = -3.4e38f;
        #pragma unroll
        for (int ni = 0; ni < NI; ++ni) mx = fmaxf(mx, acc[mi][ni][r2]);
        #pragma unroll
        for (int o = 1; o < 16; o <<= 1) mx = fmaxf(mx, __shfl_xor(mx, o));
        float sm = 0.0f;
        #pragma unroll
        for (int ni = 0; ni < NI; ++ni) sm += expf(acc[mi][ni][r2] - mx);
        #pragma unroll
        for (int o = 1; o < 16; o <<= 1) sm += __shfl_xor(sm, o);
        if (lrow == 0) {
          const int rowL = wrb + mi * 16 + q4 * 4 + r2;
          red[(rowL * WN + wc) * 2 + 0] = mx;
          red[(rowL * WN + wc) * 2 + 1] = sm;
        }
      }
    __syncthreads();
    for (int r = tid; r < BM; r += NWAVE * 64) {
      float mg = -3.4e38f, sg = 0.0f;
      #pragma unroll
      for (int w = 0; w < WN; ++w) {
        float mw = red[(r * WN + w) * 2 + 0], sw = red[(r * WN + w) * 2 + 1];
        float nm = fmaxf(mg, mw);
        sg = sg * expf(mg - nm) + sw * expf(mw - nm);
        mg = nm;
      }
      pmax[(size_t)(m0 + r) * PCH_ + blockIdx.y] = mg;
      psum[(size_t)(m0 + r) * PCH_ + blockIdx.y] = sg;
    }
  }

  if constexpr (BETAPART) {
    #pragma unroll
    for (int mi = 0; mi < MI; ++mi)
      #pragma unroll
      for (int r2 = 0; r2 < 4; ++r2) {
        float s = 0.0f;
        #pragma unroll
        for (int ni = 0; ni < NI; ++ni)
          s += acc[mi][ni][r2] * w2bv[n0 + wcb + ni * 16 + lrow];
        #pragma unroll
        for (int o = 1; o < 16; o <<= 1) s += __shfl_xor(s, o);
        if (lrow == 0)
          red[(wrb + mi * 16 + q4 * 4 + r2) * WN + wc] = s;
      }
    __syncthreads();
    for (int r = tid; r < BM; r += NWAVE * 64) {
      float s = 0.0f;
      #pragma unroll
      for (int w = 0; w < WN; ++w) s += red[r * WN + w];
      bpart[(size_t)(m0 + r) * 32 + blockIdx.y] = s;
    }
  }
}

// beta from 32 partial dots; k, bce, valid flags
__global__ __launch_bounds__(64) void beta_k_kernel(
    const float* __restrict__ bpart, const float* __restrict__ w2b,
    const int* __restrict__ mask,
    float* __restrict__ beta_out, float* __restrict__ k_out,
    float* __restrict__ bce, int* __restrict__ validf)
{
  int m = blockIdx.x, lane = threadIdx.x;
  float s = (lane < 32) ? bpart[(size_t)m * 32 + lane] : 0.0f;
  #pragma unroll
  for (int o = 32; o >= 1; o >>= 1) s += __shfl_down(s, o);
  if (lane == 0) {
    int bt = m >> 2, d1 = (m & 3) + 1;
    float beta = s + w2b[DH_];
    int mv = mask[bt];
    float bm = mv ? beta : 0.0f;
    int t = bt % T_;
    int valid = (t + d1 < T_) && mv && mask[bt + d1];
    beta_out[m] = bm;
    float sp = fmaxf(bm, 0.0f) + log1pf(expf(-fabsf(bm)));
    bce[m] = sp - (valid ? bm : 0.0f);
    validf[m] = valid;
    float sig = 1.0f / (1.0f + expf(-bm));
    int kk = (int)ceilf(sig * 8.0f);
    kk = kk < 1 ? 1 : (kk > 8 ? 8 : kk);
    if (!(sig >= 0.25f)) kk = 0;
    if (!mv) kk = 0;
    k_out[m] = (float)kk;
  }
}

// combine per-chunk (max, sumexp) partials -> nll per row
__global__ __launch_bounds__(64) void ce_reduce_kernel(
    const float* __restrict__ pmax, const float* __restrict__ psum,
    const float* __restrict__ q, const int* __restrict__ validf,
    const int* __restrict__ labels, float* __restrict__ nll)
{
  int m = blockIdx.x, lane = threadIdx.x;
  if (!validf[m]) { if (lane == 0) nll[m] = 0.0f; return; }
  float ml = -3.4e38f, sl = 0.0f;
  for (int j = lane; j < NCHUNK3_; j += 64) {
    float mj = pmax[(size_t)m * PCH_ + j], sj = psum[(size_t)m * PCH_ + j];
    float nm = fmaxf(ml, mj);
    sl = sl * expf(ml - nm) + sj * expf(mj - nm);
    ml = nm;
  }
  #pragma unroll
  for (int o = 32; o >= 1; o >>= 1) {
    float mo = __shfl_xor(ml, o), so = __shfl_xor(sl, o);
    float nm = fmaxf(ml, mo);
    sl = sl * expf(ml - nm) + so * expf(mo - nm);
    ml = nm;
  }
  if (lane == 0) {
    int bt = m >> 2, d1 = (m & 3) + 1;
    float qt = q[(size_t)m * V_ + labels[bt + d1]];
    nll[m] = -(qt - ml - logf(sl));
  }
}

__global__ __launch_bounds__(256) void loss_kernel(
    const float* __restrict__ nll, const int* __restrict__ validf,
    const float* __restrict__ bce, float* __restrict__ loss_out)
{
  __shared__ float sh[8];
  int tid = threadIdx.x;
  float snll = 0.0f, fcnt = 0.0f, sbce = 0.0f, fnsrc = 0.0f;
  for (int m = tid; m < M_; m += 256) { snll += nll[m]; fcnt += (float)validf[m]; }
  for (int bt = tid; bt < BT_; bt += 256) {
    int base = bt * 4;
    int src = validf[base] | validf[base + 1] | validf[base + 2] | validf[base + 3];
    if (src) { sbce += bce[base] + bce[base + 1] + bce[base + 2] + bce[base + 3]; fnsrc += 1.0f; }
  }
  snll = block_sum256(snll, sh);
  fcnt = block_sum256(fcnt, sh);
  sbce = block_sum256(sbce, sh);
  fnsrc = block_sum256(fnsrc, sh);
  if (tid == 0) {
    float Lq = fcnt > 0.0f ? snll / fcnt : 0.0f;
    float Lb = sbce / fmaxf(fnsrc, 1.0f);
    loss_out[0] = Lq + Lb;
  }
}

extern "C" void kernel_launch(void* const* d_in, const int* in_sizes, int n_in,
                              void* d_out, int out_size, void* d_ws, size_t ws_size,
                              hipStream_t stream) {
  const float* H    = (const float*)d_in[0];
  const int*   ids  = (const int*)d_in[1];
  const int*   mask = (const int*)d_in[2];
  const int*   labels = (const int*)d_in[3];
  const float* emb  = (const float*)d_in[4];
  const float* demb = (const float*)d_in[5];
  const float* ln_g = (const float*)d_in[6];
  const float* ln_b = (const float*)d_in[7];
  const float* W1   = (const float*)d_in[8];
  const float* b1   = (const float*)d_in[9];
  const float* W2   = (const float*)d_in[10];
  const float* b2   = (const float*)d_in[11];
  const float* Wq   = (const float*)d_in[12];
  const float* bq   = (const float*)d_in[13];
  const float* Wb   = (const float*)d_in[14];
  const float* bb   = (const float*)d_in[15];

  char* ws = (char*)d_ws; size_t off = 0;
  auto walloc = [&](size_t bytes) -> void* {
    void* p = ws + off; off = (off + bytes + 255) & ~(size_t)255; return p;
  };
  unsigned short* W1t_hi = (unsigned short*)walloc((size_t)DH_ * DM_ * 2);
  unsigned short* W1t_lo = (unsigned short*)walloc((size_t)DH_ * DM_ * 2);
  unsigned short* W2t_hi = (unsigned short*)walloc((size_t)DM_ * DH_ * 2);
  unsigned short* Wqt_hi = (unsigned short*)walloc((size_t)V_ * DM_ * 2);
  unsigned short* Xhi    = (unsigned short*)walloc((size_t)M_ * DM_ * 2);
  unsigned short* Xlo    = (unsigned short*)walloc((size_t)M_ * DM_ * 2);
  unsigned short* S2hi   = (unsigned short*)walloc((size_t)M_ * DM_ * 2);
  float* w2b    = (float*)walloc((DH_ + 1) * 4);
  float* bpart  = (float*)walloc((size_t)M_ * 32 * 4);
  float* pmax   = (float*)walloc((size_t)M_ * PCH_ * 4);
  float* psum   = (float*)walloc((size_t)M_ * PCH_ * 4);
  float* nll    = (float*)walloc(M_ * 4);
  float* bcev   = (float*)walloc(M_ * 4);
  int*   validf = (int*)walloc(M_ * 4);

  float* q_out    = (float*)d_out;
  float* beta_out = q_out + (size_t)M_ * V_;
  float* k_out    = beta_out + M_;
  float* loss_out = k_out + M_;
  // GELU activations live in d_out's q region (overwritten later by q)
  unsigned short* act_hi = (unsigned short*)d_out;
  unsigned short* act_lo = act_hi + (size_t)M_ * DH_;

  // 1) weight transposes + splits
  transpose_split_kernel<<<dim3(DH_ / 32, DM_ / 32), 256, 0, stream>>>(W1, DM_, DH_, W1t_hi, W1t_lo);
  transpose_split_kernel<<<dim3(DM_ / 32, DH_ / 32), 256, 0, stream>>>(W2, DH_, DM_, W2t_hi, nullptr);
  transpose_split_kernel<<<dim3(V_ / 32, DM_ / 32), 256, 0, stream>>>(Wq, DM_, V_, Wqt_hi, nullptr);
  // 2) embed + LN
  embed_ln_kernel<<<M_, 256, 0, stream>>>(H, ids, emb, demb, ln_g, ln_b, Xhi, Xlo);
  // 3) w2b fold
  w2b_kernel<<<DH_ + 1, 64, 0, stream>>>(W2, Wb, b2, bb, w2b);
  // 4) GEMM1: act = gelu(X @ W1 + b1), split 3-term; beta partials fused
  //    128x128 tile, 8 waves (2x4)
  gemm3p_kernel<128, 128, 8, 4, true, true, false, true, false>
      <<<dim3(M_ / 128, DH_ / 128), 512, 0, stream>>>(
      Xhi, Xlo, W1t_hi, W1t_lo, b1, DH_, DM_, nullptr, act_hi, act_lo, nullptr,
      w2b, bpart, nullptr, nullptr);
  // 5) beta/k/bce from partials
  beta_k_kernel<<<M_, 64, 0, stream>>>(bpart, w2b, mask, beta_out, k_out, bcev, validf);
  // 6) GEMM2: S2 = act @ W2 + b2, plain bf16; 128x128, 4 waves (2x2)
  gemm3p_kernel<128, 128, 4, 2, false, false, false, false, false>
      <<<dim3(M_ / 128, DM_ / 128), 256, 0, stream>>>(
      act_hi, nullptr, W2t_hi, nullptr, b2, DM_, DH_, nullptr, S2hi, nullptr, nullptr,
      nullptr, nullptr, nullptr, nullptr);
  // 7) GEMM3: q = (S2 @ Wq + bq) * mask, NT stores; CE partials fused
  //    256x256 tile, 8 waves (2x4)
  gemm3p_kernel<256, 256, 8, 4, false, false, true, false, true>
      <<<dim3(M_ / 256, V_ / 256), 512, 0, stream>>>(
      S2hi, nullptr, Wqt_hi, nullptr, bq, V_, DM_, q_out, nullptr, nullptr, mask,
      nullptr, nullptr, pmax, psum);
  // 8) CE combine
  ce_reduce_kernel<<<M_, 64, 0, stream>>>(pmax, psum, q_out, validf, labels, nll);
  // 9) final loss
  loss_kernel<<<1, 256, 0, stream>>>(nll, validf, bcev, loss_out);
}